// Round 4
// baseline (87.562 us; speedup 1.0000x reference)
//
#include <hip/hip_runtime.h>
#include <math.h>

// SACConv: B=8, C1=C2=16, K=3, S=1, H=W=64, HDIM=16, N=C1*K*K=144, L=4096
//
// out[b,l,c] = Qb[l,c] + sum_j h[l,j]*Qw[l,c*16+j]
//   Q[32768 x 272] = P[32768 x 144] @ Wcat[144 x 272]   (bf16 MFMA, K padded 160)
//   cols 0..255: (c,j) -> c*16+j from fc2_w ; cols 256..271: bias col c
//
// R4: wave = n-tile subset (w, w+4, w+8, w+12; wave3 + bias tile) over ALL 4
// m-tiles; A-frags preloaded to regs (20 ds_read_b128, once). B-frags read
// from global exactly once per block (4x dedup vs R3). Pass-1 A-frag staging
// in aligned 16B chunks (ds_write_b128, 2-way banks) instead of b16 scatter.

typedef __attribute__((ext_vector_type(8))) short short8;
typedef __attribute__((ext_vector_type(4))) float float4v;

#define NPq 144

__device__ __forceinline__ unsigned short f2bf(float f) {
    unsigned int u = __builtin_bit_cast(unsigned int, f);
    u += 0x7fffu + ((u >> 16) & 1u);
    return (unsigned short)(u >> 16);
}
__device__ __forceinline__ float bf2f(unsigned short h) {
    unsigned int u = ((unsigned int)h) << 16;
    return __builtin_bit_cast(float, u);
}

// ---------- prep: B fragments ----------
// Bfrag[(t*5+s)*64 + lane] = 8 bf16 of B[k = s*32+(lane>>4)*8+j][n = lane&15]
// t<16: B[k][n] = fc2_w[(t*144+k)*16+n]; t==16: fc2_b[n*144+k]; k>=144 -> 0
__global__ void prep_bfrag(const float* __restrict__ fc2_w,
                           const float* __restrict__ fc2_b,
                           unsigned short* __restrict__ Bfrag) {
    const int blk  = blockIdx.x;           // 85 = 17*5
    const int t    = blk / 5, s = blk % 5;
    const int lane = threadIdx.x;          // 64
    const int n    = lane & 15, q = lane >> 4;
    short8 v;
#pragma unroll
    for (int j = 0; j < 8; ++j) {
        const int k = s * 32 + q * 8 + j;
        float w = 0.f;
        if (k < NPq) w = (t < 16) ? fc2_w[(t * NPq + k) * 16 + n]
                                  : fc2_b[n * NPq + k];
        v[j] = (short)f2bf(w);
    }
    *(short8*)(Bfrag + (size_t)(blk * 64 + lane) * 8) = v;
}

// ---------- main ----------
__global__ __launch_bounds__(256, 2) void sacconv_kernel(
    const float* __restrict__ x,
    const float* __restrict__ fc1_w,
    const float* __restrict__ fc1_b,
    const unsigned short* __restrict__ Bfrag,
    float* __restrict__ out)
{
    // SH phase 1: A-fragments ushort[4 mtile][5 s][64 lane][8] (10240 hw)
    //    phase 2: Q dump ushort[64][280] (17920 hw) -> 35840 B
    __shared__ unsigned short SH[64 * 280];
    __shared__ float redA[4][64];
    __shared__ float redB[4][64];
    __shared__ float redC[4][64];
    __shared__ float redD[4][64];
    __shared__ float sb[64][8];
    __shared__ float Hl[64][20];

    const int t   = threadIdx.x;
    const int blk = blockIdx.x;     // 512
    const int b   = blk >> 6;
    const int y   = blk & 63;

    const int loc = t & 63;
    const int grp = t >> 6;         // wave id (uniform)
    const int mt  = loc >> 4;       // m-tile of this thread's loc
    const int m   = loc & 15;

    // chunk assignment: chunk c (o = c*8..c*8+7), grp g owns c = g + 4u.
    // grp 0,1: 5 chunks (40 vals); grp 2,3: 4 chunks (32 vals).
    const int nchunk = (grp < 2) ? 5 : 4;
    const int nv     = nchunk * 8;

    // ---------- pass 1: load patches -> regs + chunked A-frag LDS writes ----------
    float v[40];
    {
        float s = 0.f, mx = -1e30f;
#pragma unroll
        for (int u = 0; u < 5; ++u) {
            if (u >= nchunk) break;
            const int c = grp + 4 * u;        // chunk id, uniform per wave
            short8 pk;
#pragma unroll
            for (int j = 0; j < 8; ++j) {
                const int o  = c * 8 + j;
                const int c1 = o / 9;
                const int ii = (o % 9) / 3;
                const int jj = o % 3;
                const int yy = y + ii - 1;
                const int xx = loc + jj - 1;
                float val = 0.f;
                if (yy >= 0 && yy < 64 && xx >= 0 && xx < 64)
                    val = x[((b * 16 + c1) * 64 + yy) * 64 + xx];
                v[u * 8 + j] = val;
                pk[j] = (short)f2bf(val);
                s += val;
                mx = fmaxf(mx, val);
            }
            // one aligned 16B A-frag write: s-slot = c>>2, quad = c&3
            *(short8*)&SH[mt * 2560 + (c >> 2) * 512 + (c & 3) * 128 + m * 8] = pk;
        }
        redA[grp][loc] = s;
        redB[grp][loc] = mx;
        // zero-fill K-pad (s=4, quads 2..3 i.e. k=144..159), 2KB total
        unsigned short* zp = &SH[((grp * 5 + 4) * 64 + 32) * 8 + loc * 4];
        *(uint2*)zp = make_uint2(0u, 0u);
    }
    __syncthreads();
    if (t < 64) {
        float s  = redA[0][t] + redA[1][t] + redA[2][t] + redA[3][t];
        float mx = fmaxf(fmaxf(redB[0][t], redB[1][t]), fmaxf(redB[2][t], redB[3][t]));
        sb[t][0] = s * (1.f / 144.f);
        sb[t][1] = mx;
    }
    __syncthreads();

    // ---------- pass 2: central moments + sum exp (registers only) ----------
    {
        const float mu = sb[loc][0], mx = sb[loc][1];
        float m2 = 0.f, m3 = 0.f, m4 = 0.f, se = 0.f;
#pragma unroll
        for (int i = 0; i < 40; ++i) {
            if (i >= nv) break;
            const float d  = v[i] - mu;
            const float d2 = d * d;
            m2 += d2; m3 += d2 * d; m4 += d2 * d2;
            se += __expf(v[i] - mx);
        }
        redA[grp][loc] = m2; redB[grp][loc] = m3;
        redC[grp][loc] = m4; redD[grp][loc] = se;
    }
    __syncthreads();
    if (t < 64) {
        float m2 = redA[0][t] + redA[1][t] + redA[2][t] + redA[3][t];
        float m3 = redB[0][t] + redB[1][t] + redB[2][t] + redB[3][t];
        float m4 = redC[0][t] + redC[1][t] + redC[2][t] + redC[3][t];
        float Z  = redD[0][t] + redD[1][t] + redD[2][t] + redD[3][t];
        float var   = m2 * (1.f / 143.f);          // ddof=1
        float sigma = sqrtf(var) + 1e-6f;
        float is  = 1.f / sigma;
        float is2 = is * is;
        sb[t][2] = sigma;
        sb[t][3] = (m3 * (1.f / 144.f)) * is2 * is;
        sb[t][4] = (m4 * (1.f / 144.f)) * is2 * is2 - 3.f;
        sb[t][5] = 1.f / Z;
    }
    __syncthreads();

    // ---------- pass 3: entropy ----------
    {
        const float mx = sb[loc][1], invZ = sb[loc][5];
        float ent = 0.f;
#pragma unroll
        for (int i = 0; i < 40; ++i) {
            if (i >= nv) break;
            const float pr = __expf(v[i] - mx) * invZ;
            ent += pr * __logf(pr + 1e-6f);
        }
        redA[grp][loc] = ent;
    }
    __syncthreads();

    // ---------- h = relu(stats @ fc1_w^T + fc1_b) ----------
    {
        const float ent = -(redA[0][loc] + redA[1][loc] + redA[2][loc] + redA[3][loc]);
        const float s0 = sb[loc][0], s1 = sb[loc][2], s2 = sb[loc][3], s3 = sb[loc][4];
#pragma unroll
        for (int j0 = 0; j0 < 4; ++j0) {
            const int j = grp * 4 + j0;
            const float* wr = fc1_w + j * 5;
            float hv = s0 * wr[0] + s1 * wr[1] + s2 * wr[2] + s3 * wr[3]
                     + ent * wr[4] + fc1_b[j];
            Hl[loc][j] = fmaxf(hv, 0.f);
        }
    }
    // Hl consumed only after the post-MFMA barrier

    // ---------- MFMA: wave w owns n-tiles {w,w+4,w+8,w+12} (+16 if w==3) ----------
    const int w    = __builtin_amdgcn_readfirstlane(t >> 6);
    const int lane = t & 63;

    // preload ALL A-fragments (4 m-tiles x 5 K-steps), 20 ds_read_b128
    short8 af[4][5];
#pragma unroll
    for (int mm = 0; mm < 4; ++mm)
#pragma unroll
        for (int s = 0; s < 5; ++s)
            af[mm][s] = *(const short8*)&SH[((mm * 5 + s) * 64 + lane) * 8];

    float4v acc[20];
#pragma unroll
    for (int i = 0; i < 20; ++i) acc[i] = (float4v){0.f, 0.f, 0.f, 0.f};

    const short8* Bf = (const short8*)Bfrag;
    short8 bcur[5], bnxt[5];
#pragma unroll
    for (int s = 0; s < 5; ++s) bcur[s] = Bf[(w * 5 + s) * 64 + lane];

#pragma unroll
    for (int u = 0; u < 4; ++u) {
        if (u < 3) {
            const int tn = w + 4 * (u + 1);
#pragma unroll
            for (int s = 0; s < 5; ++s) bnxt[s] = Bf[(tn * 5 + s) * 64 + lane];
        } else if (w == 3) {
#pragma unroll
            for (int s = 0; s < 5; ++s) bnxt[s] = Bf[(16 * 5 + s) * 64 + lane];
        }
#pragma unroll
        for (int mm = 0; mm < 4; ++mm)
#pragma unroll
            for (int s = 0; s < 5; ++s)
                acc[u * 4 + mm] = __builtin_amdgcn_mfma_f32_16x16x32_bf16(
                    af[mm][s], bcur[s], acc[u * 4 + mm], 0, 0, 0);
#pragma unroll
        for (int s = 0; s < 5; ++s) bcur[s] = bnxt[s];
    }
    if (w == 3) {
#pragma unroll
        for (int mm = 0; mm < 4; ++mm)
#pragma unroll
            for (int s = 0; s < 5; ++s)
                acc[16 + mm] = __builtin_amdgcn_mfma_f32_16x16x32_bf16(
                    af[mm][s], bcur[s], acc[16 + mm], 0, 0, 0);
    }

    // ---------- dump Q to LDS (bf16), aliasing dead A-frag space ----------
    __syncthreads();   // all waves done reading SH A-frags
    {
        const int nn = lane & 15, qq = lane >> 4;
#pragma unroll
        for (int u = 0; u < 4; ++u) {
            const int colb = (w + 4 * u) * 16 + nn;
#pragma unroll
            for (int mm = 0; mm < 4; ++mm)
#pragma unroll
                for (int r = 0; r < 4; ++r)
                    SH[(mm * 16 + qq * 4 + r) * 280 + colb] = f2bf(acc[u * 4 + mm][r]);
        }
        if (w == 3) {
#pragma unroll
            for (int mm = 0; mm < 4; ++mm)
#pragma unroll
                for (int r = 0; r < 4; ++r)
                    SH[(mm * 16 + qq * 4 + r) * 280 + 256 + nn] = f2bf(acc[16 + mm][r]);
        }
    }
    __syncthreads();

    // ---------- fold h, write out ----------
    {
        float hv[16];
#pragma unroll
        for (int j = 0; j < 16; ++j) hv[j] = Hl[loc][j];
        const int cg = w * 4;
#pragma unroll
        for (int cc = 0; cc < 4; ++cc) {
            const int c = cg + cc;
            const unsigned short* qr = &SH[loc * 280 + c * 16];
            short8 q0 = *(const short8*)qr;
            short8 q1 = *(const short8*)(qr + 8);
            float res = bf2f(SH[loc * 280 + 256 + c]);
#pragma unroll
            for (int j = 0; j < 8; ++j) res += hv[j]     * bf2f((unsigned short)q0[j]);
#pragma unroll
            for (int j = 0; j < 8; ++j) res += hv[8 + j] * bf2f((unsigned short)q1[j]);
            out[(b * 16 + c) * 4096 + y * 64 + loc] = res;
        }
    }
}

extern "C" void kernel_launch(void* const* d_in, const int* in_sizes, int n_in,
                              void* d_out, int out_size, void* d_ws, size_t ws_size,
                              hipStream_t stream) {
    const float* x     = (const float*)d_in[0];
    const float* fc1_w = (const float*)d_in[1];
    const float* fc1_b = (const float*)d_in[2];
    const float* fc2_w = (const float*)d_in[3];
    const float* fc2_b = (const float*)d_in[4];
    float* out = (float*)d_out;
    unsigned short* Bfrag = (unsigned short*)d_ws;   // 85*64*8*2 = 87040 B

    prep_bfrag<<<85, 64, 0, stream>>>(fc2_w, fc2_b, Bfrag);
    sacconv_kernel<<<512, 256, 0, stream>>>(x, fc1_w, fc1_b, Bfrag, out);
}

// Round 5
// 74.632 us; speedup vs baseline: 1.1733x; 1.1733x over previous
//
#include <hip/hip_runtime.h>
#include <math.h>

// SACConv: B=8, C1=C2=16, K=3, S=1, H=W=64, HDIM=16, N=C1*K*K=144, L=4096
//
// out[b,l,c] = Qb[l,c] + sum_j h[l,j]*Qw[l,c*16+j]
//   Q[32768 x 272] = P[32768 x 144] @ Wcat[144 x 272]   (bf16 MFMA, K padded 160)
//   cols 0..255: (c,j) -> c*16+j from fc2_w ; cols 256..271: bias col c
//
// R5: stats = exactly 36 vals/thread in registers (no breaks -> no scratch);
// entropy via ln Z + mx - (sum e*v)/Z (pass 3 eliminated);
// MFMA: wave (mp=w>>1, nh=w&1) does m-pair x 9 n-tiles (tile 8 duplicated,
// bit-identical) -> ~155 VGPRs, uniform 90 MFMA/wave, 2x B dedup vs R3.

typedef __attribute__((ext_vector_type(8))) short short8;
typedef __attribute__((ext_vector_type(4))) float float4v;

#define NPq 144

__device__ __forceinline__ unsigned short f2bf(float f) {
    unsigned int u = __builtin_bit_cast(unsigned int, f);
    u += 0x7fffu + ((u >> 16) & 1u);
    return (unsigned short)(u >> 16);
}
__device__ __forceinline__ float bf2f(unsigned short h) {
    unsigned int u = ((unsigned int)h) << 16;
    return __builtin_bit_cast(float, u);
}

// ---------- prep: B fragments ----------
// Bfrag[(t*5+s)*64 + lane] = 8 bf16 of B[k = s*32+(lane>>4)*8+j][n = lane&15]
// t<16: B[k][n] = fc2_w[(t*144+k)*16+n]; t==16: fc2_b[n*144+k]; k>=144 -> 0
__global__ void prep_bfrag(const float* __restrict__ fc2_w,
                           const float* __restrict__ fc2_b,
                           unsigned short* __restrict__ Bfrag) {
    const int blk  = blockIdx.x;           // 85 = 17*5
    const int t    = blk / 5, s = blk % 5;
    const int lane = threadIdx.x;          // 64
    const int n    = lane & 15, q = lane >> 4;
    short8 v;
#pragma unroll
    for (int j = 0; j < 8; ++j) {
        const int k = s * 32 + q * 8 + j;
        float w = 0.f;
        if (k < NPq) w = (t < 16) ? fc2_w[(t * NPq + k) * 16 + n]
                                  : fc2_b[n * NPq + k];
        v[j] = (short)f2bf(w);
    }
    *(short8*)(Bfrag + (size_t)(blk * 64 + lane) * 8) = v;
}

// ---------- main ----------
__global__ __launch_bounds__(256, 2) void sacconv_kernel(
    const float* __restrict__ x,
    const float* __restrict__ fc1_w,
    const float* __restrict__ fc1_b,
    const unsigned short* __restrict__ Bfrag,
    float* __restrict__ out)
{
    // SH phase 1: A-frags ushort[4 mtile][5 s][64 lane][8]  (10240 hw)
    //    phase 2: Q dump ushort[64][280]                    (17920 hw) = 35840 B
    __shared__ unsigned short SH[64 * 280];
    __shared__ float redA[4][64];
    __shared__ float redB[4][64];
    __shared__ float redC[4][64];
    __shared__ float redD[4][64];
    __shared__ float redE[4][64];
    __shared__ float sb[64][9];      // mu, sigma, skew, kurt, ent
    __shared__ float Hl[64][21];

    const int t   = threadIdx.x;
    const int blk = blockIdx.x;     // 512
    const int b   = blk >> 6;
    const int y   = blk & 63;

    const int loc = t & 63;
    const int grp = t >> 6;         // wave id
    const int mt  = loc >> 4;       // m-tile of this thread's loc
    const int m   = loc & 15;

    // ---------- pass 1: load 36 patch vals (9 chunks of 4), stage A-frags ----------
    // chunk c = grp + 4u (u=0..8) covers o = 4c..4c+3; all 36 chunks covered.
    float v[36];
    {
        float s = 0.f, mx = -1e30f;
#pragma unroll
        for (int u = 0; u < 9; ++u) {
            const int c = grp + 4 * u;     // uniform per wave, compile-time per iter
            unsigned int lo, hi;
#pragma unroll
            for (int d = 0; d < 4; ++d) {
                const int o  = c * 4 + d;
                const int c1 = o / 9;
                const int ii = (o % 9) / 3;
                const int jj = o % 3;
                const int yy = y + ii - 1;
                const int xx = loc + jj - 1;
                float val = 0.f;
                if (yy >= 0 && yy < 64 && xx >= 0 && xx < 64)
                    val = x[((b * 16 + c1) * 64 + yy) * 64 + xx];
                v[u * 4 + d] = val;
                s += val;
                mx = fmaxf(mx, val);
                const unsigned int bf = f2bf(val);
                if (d == 0) lo = bf;
                else if (d == 1) lo |= bf << 16;
                else if (d == 2) hi = bf;
                else hi |= bf << 16;
            }
            // aligned 8B A-frag write: o0=4c -> s=c>>3, quad=(c>>1)&3, j=(c&1)*4
            unsigned short* dst = &SH[mt * 2560 + (c >> 3) * 512 + ((c >> 1) & 3) * 128
                                      + m * 8 + (c & 1) * 4];
            *(uint2*)dst = make_uint2(lo, hi);
        }
        redA[grp][loc] = s;
        redB[grp][loc] = mx;
        // zero-fill K-pad k=144..159 (s=4, quads 2..3): 1024 hw over 256 threads
        unsigned short* zp = &SH[((grp * 5 + 4) * 64 + 32) * 8 + loc * 4];
        *(uint2*)zp = make_uint2(0u, 0u);
    }
    __syncthreads();
    if (t < 64) {
        float s  = redA[0][t] + redA[1][t] + redA[2][t] + redA[3][t];
        float mx = fmaxf(fmaxf(redB[0][t], redB[1][t]), fmaxf(redB[2][t], redB[3][t]));
        sb[t][0] = s * (1.f / 144.f);
        sb[t][5] = mx;                 // temp slot for max
    }
    __syncthreads();

    // ---------- pass 2: central moments + exp sums (registers only) ----------
    {
        const float mu = sb[loc][0], mx = sb[loc][5];
        float m2 = 0.f, m3 = 0.f, m4 = 0.f, se = 0.f, sev = 0.f;
#pragma unroll
        for (int i = 0; i < 36; ++i) {
            const float d  = v[i] - mu;
            const float d2 = d * d;
            m2 += d2; m3 += d2 * d; m4 += d2 * d2;
            const float e = __expf(v[i] - mx);
            se += e; sev += e * v[i];
        }
        redA[grp][loc] = m2; redB[grp][loc] = m3;
        redC[grp][loc] = m4; redD[grp][loc] = se;
        redE[grp][loc] = sev;
    }
    __syncthreads();
    if (t < 64) {
        float m2 = redA[0][t] + redA[1][t] + redA[2][t] + redA[3][t];
        float m3 = redB[0][t] + redB[1][t] + redB[2][t] + redB[3][t];
        float m4 = redC[0][t] + redC[1][t] + redC[2][t] + redC[3][t];
        float Z  = redD[0][t] + redD[1][t] + redD[2][t] + redD[3][t];
        float S  = redE[0][t] + redE[1][t] + redE[2][t] + redE[3][t];
        float var   = m2 * (1.f / 143.f);          // ddof=1
        float sigma = sqrtf(var) + 1e-6f;
        float is  = 1.f / sigma;
        float is2 = is * is;
        sb[t][1] = sigma;
        sb[t][2] = (m3 * (1.f / 144.f)) * is2 * is;
        sb[t][3] = (m4 * (1.f / 144.f)) * is2 * is2 - 3.f;
        // entropy = -sum p ln p ; p = e/Z, e = exp(v-mx)
        sb[t][4] = __logf(Z) + sb[t][5] - S / Z;
    }
    __syncthreads();

    // ---------- h = relu(stats @ fc1_w^T + fc1_b) ----------
    {
        const float s0 = sb[loc][0], s1 = sb[loc][1], s2 = sb[loc][2],
                    s3 = sb[loc][3], s4 = sb[loc][4];
#pragma unroll
        for (int j0 = 0; j0 < 4; ++j0) {
            const int j = grp * 4 + j0;
            const float* wr = fc1_w + j * 5;
            float hv = s0 * wr[0] + s1 * wr[1] + s2 * wr[2] + s3 * wr[3]
                     + s4 * wr[4] + fc1_b[j];
            Hl[loc][j] = fmaxf(hv, 0.f);
        }
    }
    // Hl consumed only after the post-MFMA barrier

    // ---------- MFMA: wave (mp, nh) -> m-tiles {2mp,2mp+1} x n-tiles {8nh..8nh+8} ----------
    const int w    = __builtin_amdgcn_readfirstlane(t >> 6);
    const int mp   = w >> 1;
    const int nh   = w & 1;
    const int nb   = nh * 8;            // n-tile base (tile 8 done by both halves)
    const int lane = t & 63;

    short8 af[2][5];
#pragma unroll
    for (int mm = 0; mm < 2; ++mm)
#pragma unroll
        for (int s = 0; s < 5; ++s)
            af[mm][s] = *(const short8*)&SH[((2 * mp + mm) * 5 + s) * 512 + lane * 8];

    float4v acc[18];
#pragma unroll
    for (int i = 0; i < 18; ++i) acc[i] = (float4v){0.f, 0.f, 0.f, 0.f};

    const short8* Bf = (const short8*)Bfrag;
    short8 bcur[5], bnxt[5];
#pragma unroll
    for (int s = 0; s < 5; ++s) bcur[s] = Bf[((nb) * 5 + s) * 64 + lane];

#pragma unroll
    for (int u = 0; u < 9; ++u) {
        if (u < 8) {
#pragma unroll
            for (int s = 0; s < 5; ++s) bnxt[s] = Bf[((nb + u + 1) * 5 + s) * 64 + lane];
        }
#pragma unroll
        for (int mm = 0; mm < 2; ++mm)
#pragma unroll
            for (int s = 0; s < 5; ++s)
                acc[u * 2 + mm] = __builtin_amdgcn_mfma_f32_16x16x32_bf16(
                    af[mm][s], bcur[s], acc[u * 2 + mm], 0, 0, 0);
        if (u < 8) {
#pragma unroll
            for (int s = 0; s < 5; ++s) bcur[s] = bnxt[s];
        }
    }

    // ---------- dump Q to LDS (bf16), aliasing dead A-frag space ----------
    __syncthreads();   // all waves done reading SH A-frags; Hl written
    {
        const int nn = lane & 15, qq = lane >> 4;
#pragma unroll
        for (int u = 0; u < 9; ++u) {
            const int col = (nb + u) * 16 + nn;   // tile 16 -> cols 256..271 (bias)
#pragma unroll
            for (int mm = 0; mm < 2; ++mm) {
                const int rowb = (2 * mp + mm) * 16 + qq * 4;
#pragma unroll
                for (int r = 0; r < 4; ++r)
                    SH[(rowb + r) * 280 + col] = f2bf(acc[u * 2 + mm][r]);
            }
        }
    }
    __syncthreads();

    // ---------- fold h, write out ----------
    {
        float hv[16];
#pragma unroll
        for (int j = 0; j < 16; ++j) hv[j] = Hl[loc][j];
        const int cg = w * 4;
#pragma unroll
        for (int cc = 0; cc < 4; ++cc) {
            const int c = cg + cc;
            const unsigned short* qr = &SH[loc * 280 + c * 16];
            short8 q0 = *(const short8*)qr;
            short8 q1 = *(const short8*)(qr + 8);
            float res = bf2f(SH[loc * 280 + 256 + c]);
#pragma unroll
            for (int j = 0; j < 8; ++j) res += hv[j]     * bf2f((unsigned short)q0[j]);
#pragma unroll
            for (int j = 0; j < 8; ++j) res += hv[8 + j] * bf2f((unsigned short)q1[j]);
            out[(b * 16 + c) * 4096 + y * 64 + loc] = res;
        }
    }
}

extern "C" void kernel_launch(void* const* d_in, const int* in_sizes, int n_in,
                              void* d_out, int out_size, void* d_ws, size_t ws_size,
                              hipStream_t stream) {
    const float* x     = (const float*)d_in[0];
    const float* fc1_w = (const float*)d_in[1];
    const float* fc1_b = (const float*)d_in[2];
    const float* fc2_w = (const float*)d_in[3];
    const float* fc2_b = (const float*)d_in[4];
    float* out = (float*)d_out;
    unsigned short* Bfrag = (unsigned short*)d_ws;   // 85*64*8*2 = 87040 B

    prep_bfrag<<<85, 64, 0, stream>>>(fc2_w, fc2_b, Bfrag);
    sacconv_kernel<<<512, 256, 0, stream>>>(x, fc1_w, fc1_b, Bfrag, out);
}